// Round 1
// baseline (2032.782 us; speedup 1.0000x reference)
//
#include <hip/hip_runtime.h>

#define N_NODES 100000
#define N_EDGES 400000
#define N_GRAPHS 5000
#define NPG 20

// ---------------- node encoder: h0[N,52] ----------------
__global__ void k_encode_nodes(const float* __restrict__ x,
                               const float* __restrict__ atom_emb,
                               const float* __restrict__ bool_emb,
                               const float* __restrict__ Wn,
                               const float* __restrict__ bn,
                               float* __restrict__ h0) {
  int n = blockIdx.x * blockDim.x + threadIdx.x;
  if (n >= N_NODES) return;
  const float* xr = x + (size_t)n * 14;
  float* h = h0 + (size_t)n * 52;
  int ai = (int)xr[0];
  #pragma unroll
  for (int j = 0; j < 16; j++) h[j] = atom_emb[ai * 16 + j];
  float xc[10];
  #pragma unroll
  for (int k = 0; k < 10; k++) xc[k] = xr[1 + k];
  #pragma unroll
  for (int c = 0; c < 30; c++) {
    float s = bn[c];
    #pragma unroll
    for (int k = 0; k < 10; k++) s += xc[k] * Wn[k * 30 + c];
    h[16 + c] = s;
  }
  #pragma unroll
  for (int t = 0; t < 3; t++) {
    int b = (int)xr[11 + t];
    h[46 + 2 * t]     = bool_emb[2 * b];
    h[46 + 2 * t + 1] = bool_emb[2 * b + 1];
  }
}

// ---------------- edge encoder: e_full[0:E,16] + atomic loop-attr sums ----------------
__global__ void k_encode_edges(const float* __restrict__ eattr,
                               const int* __restrict__ dst,
                               const float* __restrict__ bond_emb,
                               const float* __restrict__ bool_emb,
                               const float* __restrict__ We,
                               const float* __restrict__ be,
                               float* __restrict__ e_full,
                               int* __restrict__ cnt) {
  int e = blockIdx.x * blockDim.x + threadIdx.x;
  if (e >= N_EDGES) return;
  const float* r = eattr + (size_t)e * 5;
  float row[16];
  int bi = (int)r[0];
  #pragma unroll
  for (int j = 0; j < 8; j++) row[j] = bond_emb[bi * 8 + j];
  float ec = r[1];
  row[8] = ec * We[0] + be[0];
  row[9] = ec * We[1] + be[1];
  #pragma unroll
  for (int t = 0; t < 3; t++) {
    int b = (int)r[2 + t];
    row[10 + 2 * t]     = bool_emb[2 * b];
    row[10 + 2 * t + 1] = bool_emb[2 * b + 1];
  }
  float* out = e_full + (size_t)e * 16;
  #pragma unroll
  for (int k = 0; k < 16; k++) out[k] = row[k];
  int d = dst[e];
  float* lp = e_full + (size_t)(N_EDGES + d) * 16;
  #pragma unroll
  for (int k = 0; k < 16; k++) atomicAdd(lp + k, row[k]);
  atomicAdd(cnt + d, 1);
}

// ---------------- loop_attr = sum / max(cnt,1) ----------------
__global__ void k_loop_div(float* __restrict__ e_full, const int* __restrict__ cnt) {
  int n = blockIdx.x * blockDim.x + threadIdx.x;
  if (n >= N_NODES) return;
  int c = cnt[n];
  float inv = 1.0f / (float)(c > 0 ? c : 1);
  float* lp = e_full + (size_t)(N_EDGES + n) * 16;
  #pragma unroll
  for (int k = 0; k < 16; k++) lp[k] *= inv;
}

// ---------------- single-block exclusive scan over (cnt[n]+1) ----------------
__global__ __launch_bounds__(1024) void k_scan(const int* __restrict__ cnt,
                                               int* __restrict__ indptr,
                                               int* __restrict__ cursor) {
  __shared__ int sums[1024];
  int t = threadIdx.x;
  const int per = (N_NODES + 1023) / 1024;  // 98
  int beg = t * per;
  int end = beg + per; if (end > N_NODES) end = N_NODES;
  int s = 0;
  for (int i = beg; i < end && i < N_NODES; i++) s += cnt[i] + 1;
  sums[t] = s;
  __syncthreads();
  for (int off = 1; off < 1024; off <<= 1) {
    int v = (t >= off) ? sums[t - off] : 0;
    __syncthreads();
    sums[t] += v;
    __syncthreads();
  }
  int run = (t > 0) ? sums[t - 1] : 0;
  for (int i = beg; i < end && i < N_NODES; i++) {
    indptr[i] = run;
    cursor[i] = run;
    run += cnt[i] + 1;
  }
  if (t == 1023) indptr[N_NODES] = sums[1023];
}

// ---------------- CSR fill (edges then self-loops) ----------------
__global__ void k_fill(const int* __restrict__ dst,
                       int* __restrict__ cursor,
                       int* __restrict__ eord) {
  int i = blockIdx.x * blockDim.x + threadIdx.x;
  if (i >= N_EDGES + N_NODES) return;
  int d = (i < N_EDGES) ? dst[i] : (i - N_EDGES);
  int p = atomicAdd(&cursor[d], 1);
  eord[p] = i;
}

// ---------------- skinny GEMM: out[N,128] = A[N,K] @ W[K,128] + b ----------------
template <int K>
__global__ __launch_bounds__(256) void k_gemm(const float* __restrict__ A,
                                              const float* __restrict__ W,
                                              const float* __restrict__ b,
                                              float* __restrict__ out,
                                              int n_rows) {
  __shared__ float Wl[K * 128];
  __shared__ float bl[128];
  for (int i = threadIdx.x; i < K * 128; i += 256) Wl[i] = W[i];
  if (threadIdx.x < 128) bl[threadIdx.x] = b[threadIdx.x];
  __syncthreads();
  int wid = (blockIdx.x * 256 + threadIdx.x) >> 6;
  int nw = (gridDim.x * 256) >> 6;
  int lane = threadIdx.x & 63;
  int c = lane * 2;
  wid = __builtin_amdgcn_readfirstlane(wid);
  for (int n = wid; n < n_rows; n += nw) {
    const float* a = A + (size_t)n * K;
    float acc0 = bl[c], acc1 = bl[c + 1];
    #pragma unroll 4
    for (int k = 0; k < K; k++) {
      float av = a[k];
      acc0 += av * Wl[k * 128 + c];
      acc1 += av * Wl[k * 128 + c + 1];
    }
    float2 o; o.x = acc0; o.y = acc1;
    *(float2*)(out + (size_t)n * 128 + c) = o;
  }
}

// ---------------- GATv2 edge pass: one wave per dst node ----------------
__global__ __launch_bounds__(256) void k_gat(const float* __restrict__ xl,
                                             const float* __restrict__ xr,
                                             const float* __restrict__ e_full,
                                             const int* __restrict__ srcA,
                                             const int* __restrict__ indptr,
                                             const int* __restrict__ eord,
                                             const float* __restrict__ Wedge,
                                             const float* __restrict__ att,
                                             const float* __restrict__ bias,
                                             float* __restrict__ logits,
                                             float* __restrict__ hout) {
  int wid = (blockIdx.x * 256 + threadIdx.x) >> 6;
  int nw = (gridDim.x * 256) >> 6;
  int lane = threadIdx.x & 63;
  int c = lane * 2;
  // per-lane Wedge columns (16 x 2), attention and bias values
  float wreg[32];
  #pragma unroll
  for (int k = 0; k < 16; k++) {
    wreg[2 * k]     = Wedge[k * 128 + c];
    wreg[2 * k + 1] = Wedge[k * 128 + c + 1];
  }
  float att0 = att[c], att1 = att[c + 1];
  float b0 = bias[c], b1 = bias[c + 1];
  wid = __builtin_amdgcn_readfirstlane(wid);
  for (int n = wid; n < N_NODES; n += nw) {
    int beg = indptr[n], end = indptr[n + 1];
    float2 xrv = *(const float2*)(xr + (size_t)n * 128 + c);
    float amax = -1e30f;
    // pass 1: logits + max
    for (int j = beg; j < end; j++) {
      int eid = eord[j];
      int s = (eid < N_EDGES) ? srcA[eid] : n;
      const float4* ep = (const float4*)(e_full + (size_t)eid * 16);
      float4 q0 = ep[0], q1 = ep[1], q2 = ep[2], q3 = ep[3];
      float ev[16] = {q0.x, q0.y, q0.z, q0.w, q1.x, q1.y, q1.z, q1.w,
                      q2.x, q2.y, q2.z, q2.w, q3.x, q3.y, q3.z, q3.w};
      float el0 = 0.f, el1 = 0.f;
      #pragma unroll
      for (int k = 0; k < 16; k++) {
        el0 += ev[k] * wreg[2 * k];
        el1 += ev[k] * wreg[2 * k + 1];
      }
      float2 xlv = *(const float2*)(xl + (size_t)s * 128 + c);
      float m0 = xlv.x + xrv.x + el0;
      float m1 = xlv.y + xrv.y + el1;
      float l0 = m0 > 0.f ? m0 : 0.2f * m0;
      float l1 = m1 > 0.f ? m1 : 0.2f * m1;
      float t = l0 * att0 + l1 * att1;
      #pragma unroll
      for (int off = 1; off < 64; off <<= 1) t += __shfl_xor(t, off, 64);
      if (lane == 0) logits[j] = t;
      amax = fmaxf(amax, t);
    }
    // pass 2: exp / denom / weighted sum
    float denom = 0.f, acc0 = 0.f, acc1 = 0.f;
    for (int j = beg; j < end; j++) {
      float a = logits[j];
      float ex = __expf(a - amax);
      int eid = eord[j];
      int s = (eid < N_EDGES) ? srcA[eid] : n;
      float2 xlv = *(const float2*)(xl + (size_t)s * 128 + c);
      acc0 += ex * xlv.x;
      acc1 += ex * xlv.y;
      denom += ex;
    }
    float inv = 1.0f / denom;
    float o0 = acc0 * inv + b0;
    float o1 = acc1 * inv + b1;
    float2 o; o.x = o0 > 0.f ? o0 : 0.f; o.y = o1 > 0.f ? o1 : 0.f;
    *(float2*)(hout + (size_t)n * 128 + c) = o;
  }
}

// ---------------- readout: global max pool over 20 contiguous nodes ----------------
__global__ void k_readout(const float* __restrict__ h, float* __restrict__ out) {
  int wid = (blockIdx.x * blockDim.x + threadIdx.x) >> 6;
  int lane = threadIdx.x & 63;
  if (wid >= N_GRAPHS) return;
  int c = lane * 2;
  float m0 = -1e30f, m1 = -1e30f;
  for (int i = 0; i < NPG; i++) {
    const float2 v = *(const float2*)(h + ((size_t)(wid * NPG + i)) * 128 + c);
    m0 = fmaxf(m0, v.x);
    m1 = fmaxf(m1, v.y);
  }
  float2 o; o.x = m0; o.y = m1;
  *(float2*)(out + (size_t)wid * 128 + c) = o;
}

extern "C" void kernel_launch(void* const* d_in, const int* in_sizes, int n_in,
                              void* d_out, int out_size, void* d_ws, size_t ws_size,
                              hipStream_t stream) {
  (void)in_sizes; (void)n_in; (void)out_size; (void)ws_size;
  const float* x        = (const float*)d_in[0];
  const int*   eindex   = (const int*)d_in[1];
  const float* eattr    = (const float*)d_in[2];
  const float* atom_emb = (const float*)d_in[4];
  const float* bond_emb = (const float*)d_in[5];
  const float* bool_emb = (const float*)d_in[6];
  const float* Wn   = (const float*)d_in[7];
  const float* bn   = (const float*)d_in[8];
  const float* We   = (const float*)d_in[9];
  const float* be   = (const float*)d_in[10];
  const float* Wl1  = (const float*)d_in[11];
  const float* bl1  = (const float*)d_in[12];
  const float* Wr1  = (const float*)d_in[13];
  const float* br1  = (const float*)d_in[14];
  const float* Wedge1 = (const float*)d_in[15];
  const float* att1 = (const float*)d_in[16];
  const float* bias1 = (const float*)d_in[17];
  const float* Wl2  = (const float*)d_in[18];
  const float* bl2  = (const float*)d_in[19];
  const float* Wr2  = (const float*)d_in[20];
  const float* br2  = (const float*)d_in[21];
  const float* Wedge2 = (const float*)d_in[22];
  const float* att2 = (const float*)d_in[23];
  const float* bias2 = (const float*)d_in[24];

  const int* srcA = eindex;
  const int* dstA = eindex + N_EDGES;

  char* p = (char*)d_ws;
  auto alloc = [&](size_t bytes) {
    char* r = p;
    p += (bytes + 255) & ~(size_t)255;
    return r;
  };
  float* h0     = (float*)alloc((size_t)N_NODES * 52 * 4);
  float* h      = (float*)alloc((size_t)N_NODES * 128 * 4);
  float* xl     = (float*)alloc((size_t)N_NODES * 128 * 4);
  float* xrb    = (float*)alloc((size_t)N_NODES * 128 * 4);
  float* efull  = (float*)alloc((size_t)(N_EDGES + N_NODES) * 16 * 4);
  int*   cnt    = (int*)alloc((size_t)N_NODES * 4);
  int*   indptr = (int*)alloc((size_t)(N_NODES + 1) * 4);
  int*   cursor = (int*)alloc((size_t)N_NODES * 4);
  int*   eord   = (int*)alloc((size_t)(N_EDGES + N_NODES) * 4);
  float* logits = (float*)alloc((size_t)(N_EDGES + N_NODES) * 4);

  hipMemsetAsync(cnt, 0, (size_t)N_NODES * 4, stream);
  hipMemsetAsync(efull + (size_t)N_EDGES * 16, 0, (size_t)N_NODES * 16 * 4, stream);

  k_encode_nodes<<<(N_NODES + 255) / 256, 256, 0, stream>>>(x, atom_emb, bool_emb, Wn, bn, h0);
  k_encode_edges<<<(N_EDGES + 255) / 256, 256, 0, stream>>>(eattr, dstA, bond_emb, bool_emb, We, be, efull, cnt);
  k_loop_div<<<(N_NODES + 255) / 256, 256, 0, stream>>>(efull, cnt);
  k_scan<<<1, 1024, 0, stream>>>(cnt, indptr, cursor);
  k_fill<<<(N_EDGES + N_NODES + 255) / 256, 256, 0, stream>>>(dstA, cursor, eord);

  // layer 1 (K=52)
  k_gemm<52><<<1024, 256, 0, stream>>>(h0, Wl1, bl1, xl, N_NODES);
  k_gemm<52><<<1024, 256, 0, stream>>>(h0, Wr1, br1, xrb, N_NODES);
  k_gat<<<2048, 256, 0, stream>>>(xl, xrb, efull, srcA, indptr, eord, Wedge1, att1, bias1, logits, h);

  // layer 2 (K=128)
  k_gemm<128><<<1024, 256, 0, stream>>>(h, Wl2, bl2, xl, N_NODES);
  k_gemm<128><<<1024, 256, 0, stream>>>(h, Wr2, br2, xrb, N_NODES);
  k_gat<<<2048, 256, 0, stream>>>(xl, xrb, efull, srcA, indptr, eord, Wedge2, att2, bias2, logits, h);

  // layer 3 (shared weights with layer 2)
  k_gemm<128><<<1024, 256, 0, stream>>>(h, Wl2, bl2, xl, N_NODES);
  k_gemm<128><<<1024, 256, 0, stream>>>(h, Wr2, br2, xrb, N_NODES);
  k_gat<<<2048, 256, 0, stream>>>(xl, xrb, efull, srcA, indptr, eord, Wedge2, att2, bias2, logits, h);

  k_readout<<<(N_GRAPHS * 64 + 255) / 256, 256, 0, stream>>>(h, (float*)d_out);
}